// Round 1
// baseline (17650.757 us; speedup 1.0000x reference)
//
#include <hip/hip_runtime.h>
#include <math.h>

// 2-layer LSTM decoder, H=100, T=8192 encode + F=1024 future steps, fp32.
// Three persistent blocks (3 CUs), 256 threads (4 waves) each:
//   block 0 (A) : layer-1 recurrence. gates1 = w_ih1*x + w_hh1*h1 + b. h1 -> ring1.
//   block 1 (A2): feed-forward pre2 = w_ih2*h1 + b_ih2 + b_hh2. ring1 -> ring2.
//   block 2 (B) : layer-2 recurrence gates2 = pre2 + w_hh2*h2; y = h2.w_lin + b.
//
// Changes vs previous version (sync-latency pass):
//  * Spin loops poll with RELAXED agent loads; ONE acquire fence after the wait
//    (old ACQUIRE-per-poll emitted buffer_inv per iteration -> L2 thrash).
//  * All threads spin on their own cached counter (no tid0+LDS+barrier bounce).
//  * Gate remap: wave w owns cells 25w..25w+24; lanes 0-24 compute (i,f) rows,
//    lanes 32-56 compute (g,o) rows. Gather is shfl_xor(32), no g[] LDS pass.
//  * h-state double-buffered in LDS -> ONE barrier per step (reads buf[t&1],
//    writes buf[(t+1)&1]; the barrier separates cross-window write->read).
//  * Future phase: recurrent dot computed BEFORE waiting on upstream (dot needs
//    only block-local h); encode phase keeps wait-first so ring-load latency
//    hides under the dot.
//  * Ring/y_slot stores are write-through relaxed agent atomics (release's
//    wbl2 finds nothing dirty). out[] store moved off the release path.
// Counters monotone <= 9217, so 0xAA poison sanitizes to 0.

#define HH 100
#define NT 256
#define ROWS 400
#define SPIN_CAP 2000000u

#define OFF_APROG  0
#define OFF_P2PROG 128
#define OFF_BPROG  256
#define OFF_YPROG  384
#define OFF_YSLOT  512     // (F+1) floats, F<=1024 -> 4.1 KB
#define OFF_RING   16384

__device__ __forceinline__ float rl(float v, int k) {
    return __int_as_float(__builtin_amdgcn_readlane(__float_as_int(v), k));
}
__device__ __forceinline__ unsigned san(unsigned v) { return v > 0x00FFFFFFu ? 0u : v; }
__device__ __forceinline__ void rel(unsigned* p, unsigned v) {
    __hip_atomic_store(p, v, __ATOMIC_RELEASE, __HIP_MEMORY_SCOPE_AGENT);
}
__device__ __forceinline__ float ld_f(const float* p) {
    return __hip_atomic_load((float*)p, __ATOMIC_RELAXED, __HIP_MEMORY_SCOPE_AGENT);
}
__device__ __forceinline__ void st_wt(float* p, float v) {
    __hip_atomic_store(p, v, __ATOMIC_RELAXED, __HIP_MEMORY_SCOPE_AGENT);
}
// All-thread spin: RELAXED polls + one acquire fence on success.
// cache is per-thread monotone; if it already covers `need`, the fence that
// accompanied its observation already ordered the matching data.
__device__ __forceinline__ void wait_ge(unsigned* p, unsigned need, unsigned& cache) {
    if (cache >= need) return;
    unsigned s = 0;
    do {
        cache = san(__hip_atomic_load(p, __ATOMIC_RELAXED, __HIP_MEMORY_SCOPE_AGENT));
    } while (cache < need && ++s < SPIN_CAP);
    __builtin_amdgcn_fence(__ATOMIC_ACQUIRE, "agent");
}
__device__ __forceinline__ float fast_sigm(float x) {
    return __builtin_amdgcn_rcpf(1.0f + __expf(-x));
}
__device__ __forceinline__ float fast_tanh(float x) {
    return fmaf(-2.0f, __builtin_amdgcn_rcpf(1.0f + __expf(2.0f * x)), 1.0f);
}

// accA += dot(w0, h), accB += dot(w1, h); h distributed lane-indexed:
// hv0 lane k holds h[k] (k<64), hv1 lane k holds h[64+k] (k<36).
__device__ __forceinline__ void dot2rows(const float* w0, const float* w1,
                                         float hv0, float hv1,
                                         float& accA, float& accB) {
    float a0 = 0.f, a1 = 0.f, b0 = 0.f, b1 = 0.f;
    #pragma unroll
    for (int k = 0; k < 64; k += 2) {
        float h0 = rl(hv0, k), h1 = rl(hv0, k + 1);
        a0 = fmaf(w0[k],     h0, a0);
        a1 = fmaf(w0[k + 1], h1, a1);
        b0 = fmaf(w1[k],     h0, b0);
        b1 = fmaf(w1[k + 1], h1, b1);
    }
    #pragma unroll
    for (int k = 0; k < 36; k += 2) {
        float h0 = rl(hv1, k), h1 = rl(hv1, k + 1);
        a0 = fmaf(w0[64 + k],     h0, a0);
        a1 = fmaf(w0[64 + k + 1], h1, a1);
        b0 = fmaf(w1[64 + k],     h0, b0);
        b1 = fmaf(w1[64 + k + 1], h1, b1);
    }
    accA += (a0 + a1);
    accB += (b0 + b1);
}

extern "C" __global__ void __launch_bounds__(NT, 1)
decoder_kernel(const float* __restrict__ input,
               const float* __restrict__ enc_h,
               const float* __restrict__ enc_c,
               const float* __restrict__ w_ih1,
               const float* __restrict__ w_hh1,
               const float* __restrict__ b_ih1,
               const float* __restrict__ b_hh1,
               const float* __restrict__ w_ih2,
               const float* __restrict__ w_hh2,
               const float* __restrict__ b_ih2,
               const float* __restrict__ b_hh2,
               const float* __restrict__ w_lin,
               const float* __restrict__ b_lin,
               float* __restrict__ out,
               char* __restrict__ ws,
               int T, int F, int S)
{
    const int tid = threadIdx.x;
    const int l = tid & 63;
    const int w = tid >> 6;
    unsigned* a_prog  = (unsigned*)(ws + OFF_APROG);
    unsigned* p2_prog = (unsigned*)(ws + OFF_P2PROG);
    unsigned* b_prog  = (unsigned*)(ws + OFF_BPROG);
    unsigned* y_prog  = (unsigned*)(ws + OFF_YPROG);
    float* y_slot = (float*)(ws + OFF_YSLOT);
    float* ring1  = (float*)(ws + OFF_RING);
    float* ring2  = ring1 + (size_t)S * HH;
    const int smask = S - 1;
    const int TOT = T + F;

    // Gate lane mapping (blocks A and B): wave w owns cells 25w..25w+24.
    // lanes 0-24: rows cell (i), cell+100 (f); lanes 32-56: cell+200 (g), cell+300 (o).
    const bool gi_lane = (l < 25);
    const bool go_lane = (l >= 32 && l < 57);
    const int cell = 25 * w + (gi_lane ? l : (go_lane ? (l - 32) : 0));
    const int gj0 = gi_lane ? cell : (go_lane ? cell + 200 : 0);
    const int gj1 = gi_lane ? cell + 100 : (go_lane ? cell + 300 : 0);

    if (blockIdx.x == 0) {
        // ================= A: layer-1 recurrence =================
        __shared__ __align__(16) float h1s[2][128];
        float w0[HH], w1[HH];
        const float wx0 = w_ih1[gj0];
        const float wx1 = w_ih1[gj1];
        const float bi0 = b_ih1[gj0] + b_hh1[gj0];
        const float bi1 = b_ih1[gj1] + b_hh1[gj1];
        #pragma unroll
        for (int k = 0; k < HH; ++k) w0[k] = w_hh1[gj0 * HH + k];
        #pragma unroll
        for (int k = 0; k < HH; ++k) w1[k] = w_hh1[gj1 * HH + k];
        float c1 = gi_lane ? enc_c[cell] : 0.f;
        if (tid < 128) { h1s[0][tid] = 0.f; h1s[1][tid] = 0.f; }
        __syncthreads();
        if (tid < HH) h1s[0][tid] = enc_h[tid];
        __syncthreads();

        unsigned cp2 = 0, cy = 0;
        for (int t = 0; t < TOT; ++t) {
            const float* hb = h1s[t & 1];
            float x = 0.f;
            if (t < T) x = input[t];               // issue early, used after dot
            float hv0 = hb[l];
            float hv1 = hb[64 + l];                // lanes >=36 hold 0/junk, never readlaned
            float accA = bi0, accB = bi1;
            dot2rows(w0, w1, hv0, hv1, accA, accB);
            if (t >= T) {                          // future: dot done first, now wait for y
                wait_ge(y_prog, (unsigned)(t - T + 1), cy);
                x = ld_f(&y_slot[t - T]);
            }
            accA = fmaf(x, wx0, accA);
            accB = fmaf(x, wx1, accB);
            float vA = go_lane ? fast_tanh(accA) : fast_sigm(accA);  // i or g
            float vB = fast_sigm(accB);                              // f or o
            float gg = __shfl_xor(vA, 32);
            float go = __shfl_xor(vB, 32);
            // ring1 overwrite guard: A2 consumed slot when p2_prog passed it
            if (t >= S) wait_ge(p2_prog, (unsigned)(t - S + 1), cp2);
            if (gi_lane) {
                c1 = fmaf(vB, c1, vA * gg);
                float h = go * fast_tanh(c1);
                h1s[(t + 1) & 1][cell] = h;
                st_wt(&ring1[(size_t)(t & smask) * HH + cell], h);
            }
            __syncthreads();                       // drains all waves' ring1 stores
            if (tid == 0) rel(a_prog, (unsigned)(t + 1));
        }
    } else if (blockIdx.x == 1) {
        // ================= A2: pre2 = w_ih2*h1 + biases (no recurrence) =====
        const bool has2 = tid < (ROWS - NT);       // tid < 144 owns a second row
        const int j0 = tid, j1 = has2 ? NT + tid : 0;
        float w0[HH], w1[HH];
        const float bi0 = b_ih2[j0] + b_hh2[j0];
        const float bi1 = b_ih2[j1] + b_hh2[j1];
        #pragma unroll
        for (int k = 0; k < HH; ++k) w0[k] = w_ih2[j0 * HH + k];
        #pragma unroll
        for (int k = 0; k < HH; ++k) w1[k] = w_ih2[j1 * HH + k];

        unsigned ca = 0, cb = 0;
        for (int t = 0; t < TOT; ++t) {
            wait_ge(a_prog, (unsigned)(t + 1), ca);
            const float* rp = ring1 + (size_t)(t & smask) * HH;
            float hv0 = ld_f(rp + l);
            float hv1 = (l < 36) ? ld_f(rp + 64 + l) : 0.f;
            float accA = bi0, accB = bi1;
            dot2rows(w0, w1, hv0, hv1, accA, accB);
            // ring2 overwrite guard: B consumed slot when b_prog passed it
            if (t >= S) wait_ge(b_prog, (unsigned)(t - S + 1), cb);
            float* wp = ring2 + (size_t)(t & smask) * ROWS;
            st_wt(&wp[j0], accA);
            if (has2) st_wt(&wp[j1], accB);
            __syncthreads();                       // drains all waves' ring2 stores
            if (tid == 0) rel(p2_prog, (unsigned)(t + 1));
        }
    } else {
        // ================= B: layer-2 recurrence + output =================
        __shared__ __align__(16) float h2s[2][128];
        __shared__ float yp2[2][4];
        float w0[HH], w1[HH];
        #pragma unroll
        for (int k = 0; k < HH; ++k) w0[k] = w_hh2[gj0 * HH + k];
        #pragma unroll
        for (int k = 0; k < HH; ++k) w1[k] = w_hh2[gj1 * HH + k];
        const float wl = gi_lane ? w_lin[cell] : 0.f;
        const float bl = b_lin[0];
        float c2 = 0.f;
        if (tid < 128) { h2s[0][tid] = 0.f; h2s[1][tid] = 0.f; }
        __syncthreads();

        unsigned cp = 0;
        for (int t = 0; t < TOT; ++t) {
            // Emit previous step's y right after its barrier (all partials drained).
            if (tid == 0 && t > 0) {
                const float* yq = yp2[(t - 1) & 1];
                float y = yq[0] + yq[1] + yq[2] + yq[3] + bl;
                if (t - 1 >= T - 1) {
                    st_wt(&y_slot[(t - 1) - (T - 1)], y);
                    rel(y_prog, (unsigned)(t - T + 1));   // release orders y_slot store
                }
                rel(b_prog, (unsigned)t);                 // step t-1's ring2 reads drained at BAR
                out[t - 1] = y;
            }
            const float* hb = h2s[t & 1];
            float hv0 = hb[l];
            float hv1 = hb[64 + l];
            const float* pp = ring2 + (size_t)(t & smask) * ROWS;
            float accA = 0.f, accB = 0.f, preA, preB;
            if (t < T) {      // encode: wait first so pre2 load latency hides under dot
                wait_ge(p2_prog, (unsigned)(t + 1), cp);
                preA = ld_f(pp + gj0);
                preB = ld_f(pp + gj1);
                dot2rows(w0, w1, hv0, hv1, accA, accB);
            } else {          // future: dot on local h2 first, then wait
                dot2rows(w0, w1, hv0, hv1, accA, accB);
                wait_ge(p2_prog, (unsigned)(t + 1), cp);
                preA = ld_f(pp + gj0);
                preB = ld_f(pp + gj1);
            }
            accA += preA;
            accB += preB;
            float vA = go_lane ? fast_tanh(accA) : fast_sigm(accA);  // i or g
            float vB = fast_sigm(accB);                              // f or o
            float gg = __shfl_xor(vA, 32);
            float go = __shfl_xor(vB, 32);
            float py = 0.f;
            if (gi_lane) {
                c2 = fmaf(vB, c2, vA * gg);
                float h = go * fast_tanh(c2);
                h2s[(t + 1) & 1][cell] = h;
                py = h * wl;
            }
            // wave-level y partial: lanes 0-24 valid, others 0
            py += __shfl_down(py, 32);
            py += __shfl_down(py, 16);
            py += __shfl_down(py, 8);
            py += __shfl_down(py, 4);
            py += __shfl_down(py, 2);
            py += __shfl_down(py, 1);
            if (l == 0) yp2[t & 1][w] = py;
            __syncthreads();   // drains ring2 reads + h2s/yp writes
        }
        if (tid == 0) {        // final step's y
            const float* yq = yp2[(TOT - 1) & 1];
            out[TOT - 1] = yq[0] + yq[1] + yq[2] + yq[3] + bl;
        }
    }
}

extern "C" void kernel_launch(void* const* d_in, const int* in_sizes, int n_in,
                              void* d_out, int out_size, void* d_ws, size_t ws_size,
                              hipStream_t stream) {
    const float* input = (const float*)d_in[0];
    const float* enc_h = (const float*)d_in[1];
    const float* enc_c = (const float*)d_in[2];
    const float* w_ih1 = (const float*)d_in[3];
    const float* w_hh1 = (const float*)d_in[4];
    const float* b_ih1 = (const float*)d_in[5];
    const float* b_hh1 = (const float*)d_in[6];
    const float* w_ih2 = (const float*)d_in[7];
    const float* w_hh2 = (const float*)d_in[8];
    const float* b_ih2 = (const float*)d_in[9];
    const float* b_hh2 = (const float*)d_in[10];
    const float* w_lin = (const float*)d_in[11];
    const float* b_lin = (const float*)d_in[12];
    (void)n_in;

    int T = in_sizes[0];
    int F = out_size - T;
    if (F < 0) F = 0;

    // largest power-of-two ring slot count that fits both rings in d_ws
    int S = 16;
    while ((size_t)OFF_RING + (size_t)S * 2 * (HH + ROWS) * 4 <= ws_size && S < 8192)
        S <<= 1;

    decoder_kernel<<<dim3(3), dim3(NT), 0, stream>>>(
        input, enc_h, enc_c, w_ih1, w_hh1, b_ih1, b_hh1,
        w_ih2, w_hh2, b_ih2, b_hh2, w_lin, b_lin,
        (float*)d_out, (char*)d_ws, T, F, S);
}